// Round 4
// baseline (1014.685 us; speedup 1.0000x reference)
//
#include <hip/hip_runtime.h>

#define Nn 16384
#define Ee 32768
#define NL (Nn * 32)

typedef _Float16 hf16;
typedef _Float16 half8 __attribute__((ext_vector_type(8)));
typedef float f32x16 __attribute__((ext_vector_type(16)));

__device__ __forceinline__ float gelu_f(float x) {
    return 0.5f * x * (1.0f + erff(x * 0.7071067811865476f));
}

__device__ __forceinline__ f32x16 zero16() {
    f32x16 v;
#pragma unroll
    for (int r = 0; r < 16; ++r) v[r] = 0.0f;
    return v;
}

// ---------------- projector (+ zero deg/cursor), thread = node ----------------
__global__ __launch_bounds__(256) void proj_kernel(
    const float* __restrict__ nodes, const float* __restrict__ grid2,
    const float* __restrict__ w1, const float* __restrict__ b1,
    const float* __restrict__ w2, const float* __restrict__ b2,
    float* __restrict__ x0, int* __restrict__ deg_i, int* __restrict__ cursor)
{
    const int n = blockIdx.x * 256 + threadIdx.x;
    float in[12];
#pragma unroll
    for (int j = 0; j < 10; ++j) in[j] = nodes[n * 10 + j];
    in[10] = grid2[n * 2 + 0];
    in[11] = grid2[n * 2 + 1];
    float h[16];
#pragma unroll
    for (int j = 0; j < 16; ++j) {
        float a = b1[j];
#pragma unroll
        for (int i = 0; i < 12; ++i) a = fmaf(in[i], w1[i * 16 + j], a);
        h[j] = gelu_f(a);
    }
#pragma unroll
    for (int o = 0; o < 32; ++o) {
        float a = b2[o];
#pragma unroll
        for (int j = 0; j < 16; ++j) a = fmaf(h[j], w2[j * 32 + o], a);
        x0[(size_t)n * 32 + o] = gelu_f(a);
    }
#pragma unroll
    for (int s = 0; s < 7; ++s) { deg_i[s * Nn + n] = 0; cursor[s * Nn + n] = 0; }
}

struct EPtrs { const int* p[7]; };

// ---------------- degree count (int) ----------------
__global__ __launch_bounds__(256) void count_deg_kernel(EPtrs ei, int* __restrict__ deg_i)
{
    const int t = blockIdx.x * 256 + threadIdx.x;
    const int s = t >> 15;
    const int e = t & (Ee - 1);
    const int dst = ei.p[s][Ee + e];
    atomicAdd(&deg_i[s * Nn + dst], 1);
}

// ---------------- exclusive scan per edge set -> CSR offsets ----------------
__global__ __launch_bounds__(256) void scan_kernel(const int* __restrict__ deg_i,
                                                   int* __restrict__ off)
{
    const int s = blockIdx.x;
    const int t = threadIdx.x;
    const int* d = deg_i + (size_t)s * Nn;
    int* o = off + (size_t)s * (Nn + 1);
    int local[64];
    int sum = 0;
#pragma unroll
    for (int j = 0; j < 64; ++j) { local[j] = d[t * 64 + j]; sum += local[j]; }
    __shared__ int ps[256];
    ps[t] = sum;
    __syncthreads();
    for (int st = 1; st < 256; st <<= 1) {
        int v = (t >= st) ? ps[t - st] : 0;
        __syncthreads();
        ps[t] += v;
        __syncthreads();
    }
    int base = (t > 0) ? ps[t - 1] : 0;
#pragma unroll
    for (int j = 0; j < 64; ++j) { o[t * 64 + j] = base; base += local[j]; }
    if (t == 255) o[Nn] = base;   // == Ee
}

// ---------------- rank assignment (counting sort positions) + sorted src ----------
__global__ __launch_bounds__(256) void rank_kernel(EPtrs ei, const int* __restrict__ off,
                                                   int* __restrict__ cursor,
                                                   int* __restrict__ rank,
                                                   int* __restrict__ srcS)
{
    const int t = blockIdx.x * 256 + threadIdx.x;
    const int s = t >> 15;
    const int e = t & (Ee - 1);
    const int dst = ei.p[s][Ee + e];
    const int r = off[(size_t)s * (Nn + 1) + dst] + atomicAdd(&cursor[s * Nn + dst], 1);
    rank[(size_t)s * Ee + e] = r;
    srcS[(size_t)s * Ee + r] = ei.p[s][e];
}

// ---------------- W pre-pack into A-fragment lane order ----------------
// A-frag (32x32x16 f16): lane l -> row m = l&31 (= i), k = ks*16 + 8*(l>>5) + j.
// value = kw2[k][(l&31)*32 + nt].  Wpack: [id(14)][nt(32)][ks(4)][p(2)][lane(64)][j(8)].
__global__ __launch_bounds__(256) void wprep_kernel(const float* __restrict__ kw2,
                                                    hf16* __restrict__ Wpack)
{
    const int id = blockIdx.x >> 5;
    const int nt = blockIdx.x & 31;
    const int t = threadIdx.x;             // 256 = 4 ks * 64 lanes
    const int ks = t >> 6, lane = t & 63;
    const float* kw2l = kw2 + (size_t)id * 65536;
    half8 vh, vl;
#pragma unroll
    for (int j = 0; j < 8; ++j) {
        const int k = ks * 16 + (lane >> 5) * 8 + j;
        const float v = kw2l[(size_t)k * 1024 + (lane & 31) * 32 + nt];
        const hf16 h = (hf16)v;
        vh[j] = h;
        vl[j] = (hf16)((v - (float)h) * 1024.0f);
    }
    half8* dst = (half8*)(Wpack + ((size_t)(id * 32 + nt) * 8 + ks * 2) * 512);
    dst[0 * 64 + lane] = vh;
    dst[1 * 64 + lane] = vl;
}

// ---------------- fused: edge MLP (H) + MFMA (W x H) + in-reg dot + rank store -------
// block = 256 thr = 4 waves, 128 edges (wave w owns edge tile mt=w), nt quarter-split:
// all waves iterate the SAME 8 n-tiles (W reads L1-broadcast across waves).
__global__ __launch_bounds__(256, 3) void gemm_kernel(
    const float* __restrict__ xa, const float* __restrict__ xb,
    const int* __restrict__ esrc, const int* __restrict__ erank,
    const float* __restrict__ eattr,
    const float* __restrict__ kw1l, const float* __restrict__ kb1l,
    const hf16* __restrict__ WpackL,
    float* __restrict__ msgS)
{
    __shared__ __align__(16) hf16 hLDS[4 * 4 * 2 * 512];   // 32 KiB: [mt][ks][p][lane][j]
    const int eblk = blockIdx.x >> 2;
    const int qid = blockIdx.x & 3;
    const int t = threadIdx.x, l = t & 63, wv = t >> 6;
    half8* hp8 = (half8*)hLDS;

    // ---- phase 0: H = gelu(eattr @ kw1 + kb1), split hi/lo -> frag LDS ----
    {
        const int e_loc = t >> 1;          // 0..127
        const int hpart = t & 1;           // h in [hpart*32, hpart*32+32)
        const int mt = e_loc >> 5, colbase = e_loc & 31;
        const int eg = eblk * 128 + e_loc;
        float ea5[5];
#pragma unroll
        for (int j = 0; j < 5; ++j) ea5[j] = eattr[(size_t)eg * 5 + j];
        half8 vh[2][2], vl[2][2];
#pragma unroll
        for (int hh = 0; hh < 32; ++hh) {
            const int h = hpart * 32 + hh;
            float pre = kb1l[h];
#pragma unroll
            for (int j = 0; j < 5; ++j) pre = fmaf(ea5[j], kw1l[j * 64 + h], pre);
            const float H = gelu_f(pre);
            const hf16 hv = (hf16)H;
            vh[hh >> 4][(hh >> 3) & 1][hh & 7] = hv;
            vl[hh >> 4][(hh >> 3) & 1][hh & 7] = (hf16)((H - (float)hv) * 1024.0f);
        }
#pragma unroll
        for (int ksl = 0; ksl < 2; ++ksl)
#pragma unroll
            for (int kh = 0; kh < 2; ++kh) {
                const int f = (mt * 4 + hpart * 2 + ksl) * 2;
                hp8[f * 64 + colbase + kh * 32] = vh[ksl][kh];
                hp8[(f + 1) * 64 + colbase + kh * 32] = vl[ksl][kh];
            }
    }

    // ---- gather xs in C-layout order: lane l -> edge (l&31) of tile wv, i = (r&3)+8*(r>>2)+4*hi ----
    const int hi = l >> 5;
    const int el = eblk * 128 + wv * 32 + (l & 31);
    const int src = esrc[el];
    const int rk = erank[el];
    float xsr[16];
#pragma unroll
    for (int c = 0; c < 4; ++c) {
        float4 v = *reinterpret_cast<const float4*>(xa + (size_t)src * 32 + c * 8 + hi * 4);
        if (xb) {
            float4 u = *reinterpret_cast<const float4*>(xb + (size_t)src * 32 + c * 8 + hi * 4);
            v.x += u.x; v.y += u.y; v.z += u.z; v.w += u.w;
        }
        xsr[c * 4 + 0] = v.x; xsr[c * 4 + 1] = v.y;
        xsr[c * 4 + 2] = v.z; xsr[c * 4 + 3] = v.w;
    }

    __syncthreads();

    // ---- H fragments held in registers for this wave's edge tile ----
    half8 Hh[4], Hl[4];
#pragma unroll
    for (int ks = 0; ks < 4; ++ks) {
        Hh[ks] = hp8[((wv * 4 + ks) * 2 + 0) * 64 + l];
        Hl[ks] = hp8[((wv * 4 + ks) * 2 + 1) * 64 + l];
    }

    float4 p4;
    const hf16* wbase = WpackL + (size_t)qid * 8 * 4096;

#define LOADW(TT, WH, WL) { \
    const half8* wp = (const half8*)(wbase + (size_t)(TT) * 4096); \
    _Pragma("unroll") for (int ks = 0; ks < 4; ++ks) { \
        WH[ks] = wp[(ks * 2 + 0) * 64 + l]; \
        WL[ks] = wp[(ks * 2 + 1) * 64 + l]; } }

#define COMPUTE(TT, WH, WL) { \
    f32x16 ah = zero16(), ax = zero16(); \
    _Pragma("unroll") for (int ks = 0; ks < 4; ++ks) { \
        ah = __builtin_amdgcn_mfma_f32_32x32x16_f16(WH[ks], Hh[ks], ah, 0, 0, 0); \
        ax = __builtin_amdgcn_mfma_f32_32x32x16_f16(WL[ks], Hh[ks], ax, 0, 0, 0); \
        ax = __builtin_amdgcn_mfma_f32_32x32x16_f16(WH[ks], Hl[ks], ax, 0, 0, 0); } \
    float ph = 0.0f, px = 0.0f; \
    _Pragma("unroll") for (int r = 0; r < 16; ++r) { \
        ph = fmaf(ah[r], xsr[r], ph); px = fmaf(ax[r], xsr[r], px); } \
    float p = fmaf(px, 9.765625e-4f, ph); \
    p += __shfl_xor(p, 32); \
    p4[(TT) & 3] = p; \
    if (((TT) & 3) == 3 && l < 32) \
        *reinterpret_cast<float4*>(msgS + (size_t)rk * 32 + qid * 8 + ((TT) - 3)) = p4; }

    half8 WhA[4], WlA[4], WhB[4], WlB[4];
    LOADW(0, WhA, WlA)
#pragma unroll
    for (int g = 0; g < 4; ++g) {
        LOADW(2 * g + 1, WhB, WlB)
        COMPUTE(2 * g, WhA, WlA)
        if (g < 3) LOADW(2 * g + 2, WhA, WlA)
        COMPUTE(2 * g + 1, WhB, WlB)
    }
#undef LOADW
#undef COMPUTE
}

// ---------------- node update: x' = gelu(x@lw + lb + mean(msgS) + kb2^T mean(xs)) ----
__global__ __launch_bounds__(256) void node_update_kernel(
    const float* __restrict__ xa, const float* __restrict__ xb,
    float* __restrict__ xout, const float* __restrict__ msgS,
    const int* __restrict__ off, const int* __restrict__ srcS,
    const float* __restrict__ lw, const float* __restrict__ lb,
    const float* __restrict__ kb2l)
{
    __shared__ float lwS[1024];
    __shared__ float kbS[1024];
#pragma unroll
    for (int c = 0; c < 4; ++c) {
        lwS[threadIdx.x + 256 * c] = lw[threadIdx.x + 256 * c];
        kbS[threadIdx.x + 256 * c] = kb2l[threadIdx.x + 256 * c];
    }
    __syncthreads();

    const int g = blockIdx.x * 256 + threadIdx.x;
    const int n = g >> 2;
    const int q = g & 3;

    const int b = off[n], e = off[n + 1];
    float sum[8];
    float xsum[32];
#pragma unroll
    for (int oo = 0; oo < 8; ++oo) sum[oo] = 0.0f;
#pragma unroll
    for (int i = 0; i < 32; ++i) xsum[i] = 0.0f;
    for (int j = b; j < e; ++j) {
        const float4 m0 = *reinterpret_cast<const float4*>(msgS + (size_t)j * 32 + q * 8);
        const float4 m1 = *reinterpret_cast<const float4*>(msgS + (size_t)j * 32 + q * 8 + 4);
        sum[0] += m0.x; sum[1] += m0.y; sum[2] += m0.z; sum[3] += m0.w;
        sum[4] += m1.x; sum[5] += m1.y; sum[6] += m1.z; sum[7] += m1.w;
        const int src = srcS[j];
#pragma unroll
        for (int c = 0; c < 8; ++c) {
            float4 v = *reinterpret_cast<const float4*>(xa + (size_t)src * 32 + c * 4);
            if (xb) {
                float4 u = *reinterpret_cast<const float4*>(xb + (size_t)src * 32 + c * 4);
                v.x += u.x; v.y += u.y; v.z += u.z; v.w += u.w;
            }
            xsum[c * 4 + 0] += v.x; xsum[c * 4 + 1] += v.y;
            xsum[c * 4 + 2] += v.z; xsum[c * 4 + 3] += v.w;
        }
    }
    const float inv = (e > b) ? 1.0f / (float)(e - b) : 0.0f;
    float acc[8];
#pragma unroll
    for (int oo = 0; oo < 8; ++oo) acc[oo] = fmaf(sum[oo], inv, lb[q * 8 + oo]);

    float row[32];
#pragma unroll
    for (int i = 0; i < 32; i += 4) {
        float4 v = *reinterpret_cast<const float4*>(xa + (size_t)n * 32 + i);
        if (xb) {
            float4 u = *reinterpret_cast<const float4*>(xb + (size_t)n * 32 + i);
            v.x += u.x; v.y += u.y; v.z += u.z; v.w += u.w;
        }
        row[i + 0] = v.x; row[i + 1] = v.y; row[i + 2] = v.z; row[i + 3] = v.w;
    }
#pragma unroll
    for (int i = 0; i < 32; ++i) {
        const float xi = row[i];
        const float xm = xsum[i] * inv;
#pragma unroll
        for (int oo = 0; oo < 8; ++oo) {
            acc[oo] = fmaf(xi, lwS[i * 32 + q * 8 + oo], acc[oo]);
            acc[oo] = fmaf(xm, kbS[i * 32 + q * 8 + oo], acc[oo]);
        }
    }
    float4 o0, o1;
    o0.x = gelu_f(acc[0]); o0.y = gelu_f(acc[1]); o0.z = gelu_f(acc[2]); o0.w = gelu_f(acc[3]);
    o1.x = gelu_f(acc[4]); o1.y = gelu_f(acc[5]); o1.z = gelu_f(acc[6]); o1.w = gelu_f(acc[7]);
    *reinterpret_cast<float4*>(xout + (size_t)n * 32 + q * 8) = o0;
    *reinterpret_cast<float4*>(xout + (size_t)n * 32 + q * 8 + 4) = o1;
}

// ---------------- decoder ----------------
__global__ __launch_bounds__(256) void decode_kernel(
    const float* __restrict__ a, const float* __restrict__ b,
    const float* __restrict__ w1, const float* __restrict__ b1,
    const float* __restrict__ w2, const float* __restrict__ b2,
    float* __restrict__ out)
{
    const int n = blockIdx.x * 256 + threadIdx.x;
    float s[32];
#pragma unroll
    for (int i = 0; i < 32; ++i) s[i] = a[(size_t)n * 32 + i] + b[(size_t)n * 32 + i];
    float acc = b2[0];
#pragma unroll
    for (int j = 0; j < 16; ++j) {
        float h = b1[j];
#pragma unroll
        for (int i = 0; i < 32; ++i) h = fmaf(s[i], w1[i * 16 + j], h);
        acc = fmaf(gelu_f(h), w2[j], acc);
    }
    out[n] = acc;
}

extern "C" void kernel_launch(void* const* d_in, const int* in_sizes, int n_in,
                              void* d_out, int out_size, void* d_ws, size_t ws_size,
                              hipStream_t stream)
{
    const float* nodes = (const float*)d_in[0];
    const float* grid2 = (const float*)d_in[1];
    const int* ei[7];
    const float* ea[7];
    for (int s = 0; s < 7; ++s) {
        ei[s] = (const int*)d_in[2 + s];
        ea[s] = (const float*)d_in[9 + s];
    }
    const float* pw1 = (const float*)d_in[18];
    const float* pb1 = (const float*)d_in[19];
    const float* pw2 = (const float*)d_in[20];
    const float* pb2 = (const float*)d_in[21];
    const float* dw1 = (const float*)d_in[22];
    const float* db1 = (const float*)d_in[23];
    const float* dw2 = (const float*)d_in[24];
    const float* db2 = (const float*)d_in[25];
    const float* kw1 = (const float*)d_in[26];
    const float* kb1 = (const float*)d_in[27];
    const float* kw2 = (const float*)d_in[28];
    const float* kb2 = (const float*)d_in[29];
    const float* lw  = (const float*)d_in[30];
    const float* lb  = (const float*)d_in[31];

    float* ws  = (float*)d_ws;
    float* x0   = ws + 0 * (size_t)NL;
    float* n11  = ws + 1 * (size_t)NL;
    float* n12  = ws + 2 * (size_t)NL;
    float* n22  = ws + 3 * (size_t)NL;
    float* n23  = ws + 4 * (size_t)NL;
    float* n33  = ws + 5 * (size_t)NL;
    float* n32  = ws + 6 * (size_t)NL;
    float* n21  = ws + 7 * (size_t)NL;
    float* msgS = ws + 8 * (size_t)NL;                       // Ee*32 floats (4 MB)
    size_t cur = 8 * (size_t)NL + (size_t)Ee * 32;
    hf16* Wpack = (hf16*)(ws + cur);                         // 14*32*8*512 halves
    cur += (size_t)14 * 32 * 8 * 512 / 2;
    int* deg_i  = (int*)(ws + cur); cur += (size_t)7 * Nn;
    int* cursor = (int*)(ws + cur); cur += (size_t)7 * Nn;
    int* off    = (int*)(ws + cur); cur += (size_t)7 * (Nn + 1);
    int* rank   = (int*)(ws + cur); cur += (size_t)7 * Ee;
    int* srcS   = (int*)(ws + cur);

    proj_kernel<<<Nn / 256, 256, 0, stream>>>(nodes, grid2, pw1, pb1, pw2, pb2,
                                              x0, deg_i, cursor);

    EPtrs ep;
    for (int s = 0; s < 7; ++s) ep.p[s] = ei[s];
    count_deg_kernel<<<7 * Ee / 256, 256, 0, stream>>>(ep, deg_i);
    scan_kernel<<<7, 256, 0, stream>>>(deg_i, off);
    rank_kernel<<<7 * Ee / 256, 256, 0, stream>>>(ep, off, cursor, rank, srcS);
    wprep_kernel<<<14 * 32, 256, 0, stream>>>(kw2, Wpack);

    auto layer = [&](int i, int d, int s, const float* xa, const float* xb, float* xo) {
        const int id = i * 2 + d;
        gemm_kernel<<<(Ee / 128) * 4, 256, 0, stream>>>(
            xa, xb, ei[s], rank + (size_t)s * Ee, ea[s],
            kw1 + (size_t)id * 320, kb1 + (size_t)id * 64,
            Wpack + (size_t)id * 32 * 4096, msgS);
        node_update_kernel<<<Nn * 4 / 256, 256, 0, stream>>>(
            xa, xb, xo, msgS, off + (size_t)s * (Nn + 1), srcS + (size_t)s * Ee,
            lw + (size_t)id * 1024, lb + (size_t)id * 32, kb2 + (size_t)id * 1024);
    };
    auto gno_block = [&](int i, int s, const float* xa, const float* xb, float* xo) {
        layer(i, 0, s, xa, xb, xo);
        layer(i, 1, s, xo, nullptr, xo);
    };

    // block param index order: n11->0, n12->3, n22->1, n23->4, n33->2, n32->5, n21->6
    gno_block(0, 0, x0,  nullptr, n11);
    gno_block(3, 1, x0,  nullptr, n12);
    gno_block(1, 2, n12, nullptr, n22);
    gno_block(4, 3, n12, nullptr, n23);
    gno_block(2, 4, n23, nullptr, n33);
    gno_block(5, 5, n33, nullptr, n32);
    gno_block(6, 6, n32, n22,     n21);

    decode_kernel<<<Nn / 256, 256, 0, stream>>>(n11, n21, dw1, db1, dw2, db2, (float*)d_out);
}

// Round 5
// 620.465 us; speedup vs baseline: 1.6354x; 1.6354x over previous
//
#include <hip/hip_runtime.h>

#define Nn 16384
#define Ee 32768
#define NL (Nn * 32)

typedef _Float16 hf16;
typedef _Float16 half8 __attribute__((ext_vector_type(8)));
typedef float f32x16 __attribute__((ext_vector_type(16)));

__device__ __forceinline__ float gelu_f(float x) {
    return 0.5f * x * (1.0f + erff(x * 0.7071067811865476f));
}

__device__ __forceinline__ f32x16 zero16() {
    f32x16 v;
#pragma unroll
    for (int r = 0; r < 16; ++r) v[r] = 0.0f;
    return v;
}

struct EPtrs { const int* p[7]; };
struct EA14  { const float* p[14]; };

// ---------------- projector (+ zero deg/cursor), thread = node ----------------
__global__ __launch_bounds__(256) void proj_kernel(
    const float* __restrict__ nodes, const float* __restrict__ grid2,
    const float* __restrict__ w1, const float* __restrict__ b1,
    const float* __restrict__ w2, const float* __restrict__ b2,
    float* __restrict__ x0, int* __restrict__ deg_i, int* __restrict__ cursor)
{
    const int n = blockIdx.x * 256 + threadIdx.x;
    float in[12];
#pragma unroll
    for (int j = 0; j < 10; ++j) in[j] = nodes[n * 10 + j];
    in[10] = grid2[n * 2 + 0];
    in[11] = grid2[n * 2 + 1];
    float h[16];
#pragma unroll
    for (int j = 0; j < 16; ++j) {
        float a = b1[j];
#pragma unroll
        for (int i = 0; i < 12; ++i) a = fmaf(in[i], w1[i * 16 + j], a);
        h[j] = gelu_f(a);
    }
#pragma unroll
    for (int o = 0; o < 32; ++o) {
        float a = b2[o];
#pragma unroll
        for (int j = 0; j < 16; ++j) a = fmaf(h[j], w2[j * 32 + o], a);
        x0[(size_t)n * 32 + o] = gelu_f(a);
    }
#pragma unroll
    for (int s = 0; s < 7; ++s) { deg_i[s * Nn + n] = 0; cursor[s * Nn + n] = 0; }
}

// ---------------- degree count (int) ----------------
__global__ __launch_bounds__(256) void count_deg_kernel(EPtrs ei, int* __restrict__ deg_i)
{
    const int t = blockIdx.x * 256 + threadIdx.x;
    const int s = t >> 15;
    const int e = t & (Ee - 1);
    const int dst = ei.p[s][Ee + e];
    atomicAdd(&deg_i[s * Nn + dst], 1);
}

// ---------------- exclusive scan per edge set -> CSR offsets ----------------
__global__ __launch_bounds__(256) void scan_kernel(const int* __restrict__ deg_i,
                                                   int* __restrict__ off)
{
    const int s = blockIdx.x;
    const int t = threadIdx.x;
    const int* d = deg_i + (size_t)s * Nn;
    int* o = off + (size_t)s * (Nn + 1);
    int local[64];
    int sum = 0;
#pragma unroll
    for (int j = 0; j < 64; ++j) { local[j] = d[t * 64 + j]; sum += local[j]; }
    __shared__ int ps[256];
    ps[t] = sum;
    __syncthreads();
    for (int st = 1; st < 256; st <<= 1) {
        int v = (t >= st) ? ps[t - st] : 0;
        __syncthreads();
        ps[t] += v;
        __syncthreads();
    }
    int base = (t > 0) ? ps[t - 1] : 0;
#pragma unroll
    for (int j = 0; j < 64; ++j) { o[t * 64 + j] = base; base += local[j]; }
    if (t == 255) o[Nn] = base;   // == Ee
}

// ---------------- rank assignment: build eord (dst-sorted edge ids) + srcS ----------
__global__ __launch_bounds__(256) void rank_kernel(EPtrs ei, const int* __restrict__ off,
                                                   int* __restrict__ cursor,
                                                   int* __restrict__ eord,
                                                   int* __restrict__ srcS)
{
    const int t = blockIdx.x * 256 + threadIdx.x;
    const int s = t >> 15;
    const int e = t & (Ee - 1);
    const int dst = ei.p[s][Ee + e];
    const int r = off[(size_t)s * (Nn + 1) + dst] + atomicAdd(&cursor[s * Nn + dst], 1);
    eord[(size_t)s * Ee + r] = e;
    srcS[(size_t)s * Ee + r] = ei.p[s][e];
}

// ---------------- W pre-pack into A-fragment lane order ----------------
// A-frag (32x32x16 f16): lane l -> row m = l&31 (= i), k = ks*16 + 8*(l>>5) + j.
// value = kw2[k][(l&31)*32 + nt].  Wpack: [id(14)][nt(32)][ks(4)][p(2)][lane(64)][j(8)].
__global__ __launch_bounds__(256) void wprep_kernel(const float* __restrict__ kw2,
                                                    hf16* __restrict__ Wpack)
{
    const int id = blockIdx.x >> 5;
    const int nt = blockIdx.x & 31;
    const int t = threadIdx.x;             // 256 = 4 ks * 64 lanes
    const int ks = t >> 6, lane = t & 63;
    const float* kw2l = kw2 + (size_t)id * 65536;
    half8 vh, vl;
#pragma unroll
    for (int j = 0; j < 8; ++j) {
        const int k = ks * 16 + (lane >> 5) * 8 + j;
        const float v = kw2l[(size_t)k * 1024 + (lane & 31) * 32 + nt];
        const hf16 h = (hf16)v;
        vh[j] = h;
        vl[j] = (hf16)((v - (float)h) * 1024.0f);
    }
    half8* dst = (half8*)(Wpack + ((size_t)(id * 32 + nt) * 8 + ks * 2) * 512);
    dst[0 * 64 + lane] = vh;
    dst[1 * 64 + lane] = vl;
}

// ---------------- H pre-pack: all 14 uses, B-fragment lane order ----------------
// B-frag: lane l -> col (edge) = l&31, k = ks*16 + 8*(l>>5) + j.
// Hpack: [use(14)][tile(1024)][ks(4)][p(2)][lane(64)][j(8)] halves.
__global__ __launch_bounds__(256) void hprep_kernel(
    EA14 ea, const float* __restrict__ kw1, const float* __restrict__ kb1,
    hf16* __restrict__ Hpack)
{
    const int b = blockIdx.x;
    const int u = b >> 8;                 // use id 0..13
    const int tgrp = b & 255;
    const int t = threadIdx.x, l = t & 63, wv = t >> 6;
    const int tile = tgrp * 4 + wv;
    const int eg = tile * 32 + (l & 31);
    const float* kw1u = kw1 + (size_t)u * 320;
    const float* kb1u = kb1 + (size_t)u * 64;
    float ea5[5];
#pragma unroll
    for (int j = 0; j < 5; ++j) ea5[j] = ea.p[u][(size_t)eg * 5 + j];
    half8* hp = (half8*)Hpack;
#pragma unroll
    for (int ks = 0; ks < 4; ++ks) {
        half8 vh, vl;
#pragma unroll
        for (int j = 0; j < 8; ++j) {
            const int k = ks * 16 + (l >> 5) * 8 + j;
            float pre = kb1u[k];
#pragma unroll
            for (int q = 0; q < 5; ++q) pre = fmaf(ea5[q], kw1u[q * 64 + k], pre);
            const float H = gelu_f(pre);
            const hf16 hv = (hf16)H;
            vh[j] = hv;
            vl[j] = (hf16)((H - (float)hv) * 1024.0f);
        }
        const size_t fb = ((size_t)(u * 1024 + tile) * 8 + ks * 2) * 64;
        hp[fb + l] = vh;
        hp[fb + 64 + l] = vl;
    }
}

// ---------------- gemm: MFMA (W x H) + in-reg dot + edge-order store ----------------
// grid = 1024 (XCD-swizzled); block = 4 waves, wave -> 32-edge tile; qid -> 8 n-tiles.
// No LDS, no barriers. H/W fragments pre-packed.
__global__ __launch_bounds__(256) void gemm_kernel(
    const float* __restrict__ xa, const float* __restrict__ xb,
    const int* __restrict__ esrc,
    const hf16* __restrict__ HpackU,
    const hf16* __restrict__ WpackL,
    float* __restrict__ msgS)
{
    // same-eblk qid siblings land on the same XCD
    const int lb = ((blockIdx.x & 7) << 7) + (blockIdx.x >> 3);
    const int eblk = lb >> 2;
    const int qid = lb & 3;
    const int t = threadIdx.x, l = t & 63, wv = t >> 6;
    const int tile = eblk * 4 + wv;

    // ---- H fragments (global, pre-packed) ----
    const half8* hp = (const half8*)HpackU + (size_t)tile * 8 * 64;
    half8 Hh[4], Hl[4];
#pragma unroll
    for (int ks = 0; ks < 4; ++ks) {
        Hh[ks] = hp[(ks * 2 + 0) * 64 + l];
        Hl[ks] = hp[(ks * 2 + 1) * 64 + l];
    }

    // ---- gather xs in C-layout order: lane l -> edge (l&31), i = (r&3)+8*(r>>2)+4*hi ----
    const int hi = l >> 5;
    const int el = tile * 32 + (l & 31);
    const int src = esrc[el];
    float xsr[16];
#pragma unroll
    for (int c = 0; c < 4; ++c) {
        float4 v = *reinterpret_cast<const float4*>(xa + (size_t)src * 32 + c * 8 + hi * 4);
        if (xb) {
            float4 u = *reinterpret_cast<const float4*>(xb + (size_t)src * 32 + c * 8 + hi * 4);
            v.x += u.x; v.y += u.y; v.z += u.z; v.w += u.w;
        }
        xsr[c * 4 + 0] = v.x; xsr[c * 4 + 1] = v.y;
        xsr[c * 4 + 2] = v.z; xsr[c * 4 + 3] = v.w;
    }

    float4 p4;
    const hf16* wbase = WpackL + (size_t)qid * 8 * 4096;

#define LOADW(TT, WH, WL) { \
    const half8* wp = (const half8*)(wbase + (size_t)(TT) * 4096); \
    _Pragma("unroll") for (int ks = 0; ks < 4; ++ks) { \
        WH[ks] = wp[(ks * 2 + 0) * 64 + l]; \
        WL[ks] = wp[(ks * 2 + 1) * 64 + l]; } }

#define COMPUTE(TT, WH, WL) { \
    f32x16 ah = zero16(), ax = zero16(); \
    _Pragma("unroll") for (int ks = 0; ks < 4; ++ks) { \
        ah = __builtin_amdgcn_mfma_f32_32x32x16_f16(WH[ks], Hh[ks], ah, 0, 0, 0); \
        ax = __builtin_amdgcn_mfma_f32_32x32x16_f16(WL[ks], Hh[ks], ax, 0, 0, 0); \
        ax = __builtin_amdgcn_mfma_f32_32x32x16_f16(WH[ks], Hl[ks], ax, 0, 0, 0); } \
    float ph = 0.0f, px = 0.0f; \
    _Pragma("unroll") for (int r = 0; r < 16; ++r) { \
        ph = fmaf(ah[r], xsr[r], ph); px = fmaf(ax[r], xsr[r], px); } \
    float p = fmaf(px, 9.765625e-4f, ph); \
    p += __shfl_xor(p, 32); \
    p4[(TT) & 3] = p; \
    if (((TT) & 3) == 3 && l < 32) \
        *reinterpret_cast<float4*>(msgS + (size_t)el * 32 + qid * 8 + ((TT) - 3)) = p4; }

    half8 WhA[4], WlA[4], WhB[4], WlB[4];
    LOADW(0, WhA, WlA)
#pragma unroll
    for (int g = 0; g < 4; ++g) {
        LOADW(2 * g + 1, WhB, WlB)
        COMPUTE(2 * g, WhA, WlA)
        if (g < 3) LOADW(2 * g + 2, WhA, WlA)
        COMPUTE(2 * g + 1, WhB, WlB)
    }
#undef LOADW
#undef COMPUTE
}

// ---------------- node update: x' = gelu(x@lw + lb + mean(msg) + kb2^T mean(xs)) ----
// thread = (node, o-quad of 4); grid = Nn*8/256 = 512
__global__ __launch_bounds__(256) void node_update_kernel(
    const float* __restrict__ xa, const float* __restrict__ xb,
    float* __restrict__ xout, const float* __restrict__ msgS,
    const int* __restrict__ off, const int* __restrict__ eord,
    const int* __restrict__ srcS,
    const float* __restrict__ lw, const float* __restrict__ lb,
    const float* __restrict__ kb2l)
{
    __shared__ float lwS[1024];
    __shared__ float kbS[1024];
#pragma unroll
    for (int c = 0; c < 4; ++c) {
        lwS[threadIdx.x + 256 * c] = lw[threadIdx.x + 256 * c];
        kbS[threadIdx.x + 256 * c] = kb2l[threadIdx.x + 256 * c];
    }
    __syncthreads();

    const int g = blockIdx.x * 256 + threadIdx.x;
    const int n = g >> 3;
    const int q = g & 7;

    const int b = off[n], e = off[n + 1];
    float sum[4];
    float xsum[32];
#pragma unroll
    for (int oo = 0; oo < 4; ++oo) sum[oo] = 0.0f;
#pragma unroll
    for (int i = 0; i < 32; ++i) xsum[i] = 0.0f;
    for (int j = b; j < e; ++j) {
        const int eid = eord[j];
        const float4 m0 = *reinterpret_cast<const float4*>(msgS + (size_t)eid * 32 + q * 4);
        sum[0] += m0.x; sum[1] += m0.y; sum[2] += m0.z; sum[3] += m0.w;
        const int src = srcS[j];
#pragma unroll
        for (int c = 0; c < 8; ++c) {
            float4 v = *reinterpret_cast<const float4*>(xa + (size_t)src * 32 + c * 4);
            if (xb) {
                float4 u = *reinterpret_cast<const float4*>(xb + (size_t)src * 32 + c * 4);
                v.x += u.x; v.y += u.y; v.z += u.z; v.w += u.w;
            }
            xsum[c * 4 + 0] += v.x; xsum[c * 4 + 1] += v.y;
            xsum[c * 4 + 2] += v.z; xsum[c * 4 + 3] += v.w;
        }
    }
    const float inv = (e > b) ? 1.0f / (float)(e - b) : 0.0f;
    float acc[4];
#pragma unroll
    for (int oo = 0; oo < 4; ++oo) acc[oo] = fmaf(sum[oo], inv, lb[q * 4 + oo]);

    float row[32];
#pragma unroll
    for (int i = 0; i < 32; i += 4) {
        float4 v = *reinterpret_cast<const float4*>(xa + (size_t)n * 32 + i);
        if (xb) {
            float4 u = *reinterpret_cast<const float4*>(xb + (size_t)n * 32 + i);
            v.x += u.x; v.y += u.y; v.z += u.z; v.w += u.w;
        }
        row[i + 0] = v.x; row[i + 1] = v.y; row[i + 2] = v.z; row[i + 3] = v.w;
    }
#pragma unroll
    for (int i = 0; i < 32; ++i) {
        const float xi = row[i];
        const float xm = xsum[i] * inv;
#pragma unroll
        for (int oo = 0; oo < 4; ++oo) {
            acc[oo] = fmaf(xi, lwS[i * 32 + q * 4 + oo], acc[oo]);
            acc[oo] = fmaf(xm, kbS[i * 32 + q * 4 + oo], acc[oo]);
        }
    }
    float4 o0;
    o0.x = gelu_f(acc[0]); o0.y = gelu_f(acc[1]);
    o0.z = gelu_f(acc[2]); o0.w = gelu_f(acc[3]);
    *reinterpret_cast<float4*>(xout + (size_t)n * 32 + q * 4) = o0;
}

// ---------------- decoder ----------------
__global__ __launch_bounds__(256) void decode_kernel(
    const float* __restrict__ a, const float* __restrict__ b,
    const float* __restrict__ w1, const float* __restrict__ b1,
    const float* __restrict__ w2, const float* __restrict__ b2,
    float* __restrict__ out)
{
    const int n = blockIdx.x * 256 + threadIdx.x;
    float s[32];
#pragma unroll
    for (int i = 0; i < 32; ++i) s[i] = a[(size_t)n * 32 + i] + b[(size_t)n * 32 + i];
    float acc = b2[0];
#pragma unroll
    for (int j = 0; j < 16; ++j) {
        float h = b1[j];
#pragma unroll
        for (int i = 0; i < 32; ++i) h = fmaf(s[i], w1[i * 16 + j], h);
        acc = fmaf(gelu_f(h), w2[j], acc);
    }
    out[n] = acc;
}

extern "C" void kernel_launch(void* const* d_in, const int* in_sizes, int n_in,
                              void* d_out, int out_size, void* d_ws, size_t ws_size,
                              hipStream_t stream)
{
    const float* nodes = (const float*)d_in[0];
    const float* grid2 = (const float*)d_in[1];
    const int* ei[7];
    const float* ea[7];
    for (int s = 0; s < 7; ++s) {
        ei[s] = (const int*)d_in[2 + s];
        ea[s] = (const float*)d_in[9 + s];
    }
    const float* pw1 = (const float*)d_in[18];
    const float* pb1 = (const float*)d_in[19];
    const float* pw2 = (const float*)d_in[20];
    const float* pb2 = (const float*)d_in[21];
    const float* dw1 = (const float*)d_in[22];
    const float* db1 = (const float*)d_in[23];
    const float* dw2 = (const float*)d_in[24];
    const float* db2 = (const float*)d_in[25];
    const float* kw1 = (const float*)d_in[26];
    const float* kb1 = (const float*)d_in[27];
    const float* kw2 = (const float*)d_in[28];
    const float* kb2 = (const float*)d_in[29];
    const float* lw  = (const float*)d_in[30];
    const float* lb  = (const float*)d_in[31];

    // block i (param index) -> edge set
    const int i2s[7] = {0, 2, 4, 1, 3, 5, 6};

    float* ws  = (float*)d_ws;
    float* x0   = ws + 0 * (size_t)NL;
    float* n11  = ws + 1 * (size_t)NL;
    float* n12  = ws + 2 * (size_t)NL;
    float* n22  = ws + 3 * (size_t)NL;
    float* n23  = ws + 4 * (size_t)NL;
    float* n33  = ws + 5 * (size_t)NL;
    float* n32  = ws + 6 * (size_t)NL;
    float* n21  = ws + 7 * (size_t)NL;
    float* msgS = ws + 8 * (size_t)NL;                       // Ee*32 floats (4 MB)
    size_t cur = 8 * (size_t)NL + (size_t)Ee * 32;
    hf16* Wpack = (hf16*)(ws + cur);                         // 14*32*8*512 halves (3.5 MB)
    cur += (size_t)14 * 32 * 8 * 512 / 2;
    hf16* Hpack = (hf16*)(ws + cur);                         // 14*1024*8*512 halves (117 MB)
    cur += (size_t)14 * 1024 * 8 * 512 / 2;
    int* deg_i  = (int*)(ws + cur); cur += (size_t)7 * Nn;
    int* cursor = (int*)(ws + cur); cur += (size_t)7 * Nn;
    int* off    = (int*)(ws + cur); cur += (size_t)7 * (Nn + 1) + 1;
    int* eord   = (int*)(ws + cur); cur += (size_t)7 * Ee;
    int* srcS   = (int*)(ws + cur);

    proj_kernel<<<Nn / 256, 256, 0, stream>>>(nodes, grid2, pw1, pb1, pw2, pb2,
                                              x0, deg_i, cursor);

    EPtrs ep;
    for (int s = 0; s < 7; ++s) ep.p[s] = ei[s];
    count_deg_kernel<<<7 * Ee / 256, 256, 0, stream>>>(ep, deg_i);
    scan_kernel<<<7, 256, 0, stream>>>(deg_i, off);
    rank_kernel<<<7 * Ee / 256, 256, 0, stream>>>(ep, off, cursor, eord, srcS);
    wprep_kernel<<<14 * 32, 256, 0, stream>>>(kw2, Wpack);

    EA14 ea14;
    for (int u = 0; u < 14; ++u) ea14.p[u] = ea[i2s[u >> 1]];
    hprep_kernel<<<14 * 256, 256, 0, stream>>>(ea14, kw1, kb1, Hpack);

    auto layer = [&](int i, int d, int s, const float* xa, const float* xb, float* xo) {
        const int id = i * 2 + d;
        gemm_kernel<<<1024, 256, 0, stream>>>(
            xa, xb, ei[s],
            Hpack + (size_t)id * 1024 * 8 * 512,
            Wpack + (size_t)id * 32 * 4096, msgS);
        node_update_kernel<<<Nn * 8 / 256, 256, 0, stream>>>(
            xa, xb, xo, msgS, off + (size_t)s * (Nn + 1),
            eord + (size_t)s * Ee, srcS + (size_t)s * Ee,
            lw + (size_t)id * 1024, lb + (size_t)id * 32, kb2 + (size_t)id * 1024);
    };
    auto gno_block = [&](int i, int s, const float* xa, const float* xb, float* xo) {
        layer(i, 0, s, xa, xb, xo);
        layer(i, 1, s, xo, nullptr, xo);
    };

    // block param index order: n11->0, n12->3, n22->1, n23->4, n33->2, n32->5, n21->6
    gno_block(0, 0, x0,  nullptr, n11);
    gno_block(3, 1, x0,  nullptr, n12);
    gno_block(1, 2, n12, nullptr, n22);
    gno_block(4, 3, n12, nullptr, n23);
    gno_block(2, 4, n23, nullptr, n33);
    gno_block(5, 5, n33, nullptr, n32);
    gno_block(6, 6, n32, n22,     n21);

    decode_kernel<<<Nn / 256, 256, 0, stream>>>(n11, n21, dw1, db1, dw2, db2, (float*)d_out);
}

// Round 6
// 600.849 us; speedup vs baseline: 1.6888x; 1.0326x over previous
//
#include <hip/hip_runtime.h>

#define Nn 16384
#define Ee 32768
#define NL (Nn * 32)

typedef _Float16 hf16;
typedef _Float16 half8 __attribute__((ext_vector_type(8)));
typedef float f32x16 __attribute__((ext_vector_type(16)));

__device__ __forceinline__ float gelu_f(float x) {
    return 0.5f * x * (1.0f + erff(x * 0.7071067811865476f));
}

__device__ __forceinline__ f32x16 zero16() {
    f32x16 v;
#pragma unroll
    for (int r = 0; r < 16; ++r) v[r] = 0.0f;
    return v;
}

struct EPtrs { const int* p[7]; };
struct EA14  { const float* p[14]; };

// ---------------- projector (+ zero deg/cursor), thread = node ----------------
__global__ __launch_bounds__(256) void proj_kernel(
    const float* __restrict__ nodes, const float* __restrict__ grid2,
    const float* __restrict__ w1, const float* __restrict__ b1,
    const float* __restrict__ w2, const float* __restrict__ b2,
    float* __restrict__ x0, int* __restrict__ deg_i, int* __restrict__ cursor)
{
    const int n = blockIdx.x * 256 + threadIdx.x;
    float in[12];
#pragma unroll
    for (int j = 0; j < 10; ++j) in[j] = nodes[n * 10 + j];
    in[10] = grid2[n * 2 + 0];
    in[11] = grid2[n * 2 + 1];
    float h[16];
#pragma unroll
    for (int j = 0; j < 16; ++j) {
        float a = b1[j];
#pragma unroll
        for (int i = 0; i < 12; ++i) a = fmaf(in[i], w1[i * 16 + j], a);
        h[j] = gelu_f(a);
    }
#pragma unroll
    for (int o = 0; o < 32; ++o) {
        float a = b2[o];
#pragma unroll
        for (int j = 0; j < 16; ++j) a = fmaf(h[j], w2[j * 32 + o], a);
        x0[(size_t)n * 32 + o] = gelu_f(a);
    }
#pragma unroll
    for (int s = 0; s < 7; ++s) { deg_i[s * Nn + n] = 0; cursor[s * Nn + n] = 0; }
}

// ---------------- degree count (int) ----------------
__global__ __launch_bounds__(256) void count_deg_kernel(EPtrs ei, int* __restrict__ deg_i)
{
    const int t = blockIdx.x * 256 + threadIdx.x;
    const int s = t >> 15;
    const int e = t & (Ee - 1);
    const int dst = ei.p[s][Ee + e];
    atomicAdd(&deg_i[s * Nn + dst], 1);
}

// ---------------- exclusive scan per edge set -> CSR offsets ----------------
__global__ __launch_bounds__(256) void scan_kernel(const int* __restrict__ deg_i,
                                                   int* __restrict__ off)
{
    const int s = blockIdx.x;
    const int t = threadIdx.x;
    const int* d = deg_i + (size_t)s * Nn;
    int* o = off + (size_t)s * (Nn + 1);
    int local[64];
    int sum = 0;
#pragma unroll
    for (int j = 0; j < 64; ++j) { local[j] = d[t * 64 + j]; sum += local[j]; }
    __shared__ int ps[256];
    ps[t] = sum;
    __syncthreads();
    for (int st = 1; st < 256; st <<= 1) {
        int v = (t >= st) ? ps[t - st] : 0;
        __syncthreads();
        ps[t] += v;
        __syncthreads();
    }
    int base = (t > 0) ? ps[t - 1] : 0;
#pragma unroll
    for (int j = 0; j < 64; ++j) { o[t * 64 + j] = base; base += local[j]; }
    if (t == 255) o[Nn] = base;   // == Ee
}

// ---------------- rank assignment: build eord (dst-sorted edge ids) ----------------
__global__ __launch_bounds__(256) void rank_kernel(EPtrs ei, const int* __restrict__ off,
                                                   int* __restrict__ cursor,
                                                   int* __restrict__ eord)
{
    const int t = blockIdx.x * 256 + threadIdx.x;
    const int s = t >> 15;
    const int e = t & (Ee - 1);
    const int dst = ei.p[s][Ee + e];
    const int r = off[(size_t)s * (Nn + 1) + dst] + atomicAdd(&cursor[s * Nn + dst], 1);
    eord[(size_t)s * Ee + r] = e;
}

// ---------------- W pre-pack into A-fragment lane order ----------------
// A-frag (32x32x16 f16): lane l -> row m = l&31 (= i), k = ks*16 + 8*(l>>5) + j.
// value = kw2[k][(l&31)*32 + nt].  Wpack: [id(14)][nt(32)][ks(4)][p(2)][lane(64)][j(8)].
__global__ __launch_bounds__(256) void wprep_kernel(const float* __restrict__ kw2,
                                                    hf16* __restrict__ Wpack)
{
    const int id = blockIdx.x >> 5;
    const int nt = blockIdx.x & 31;
    const int t = threadIdx.x;             // 256 = 4 ks * 64 lanes
    const int ks = t >> 6, lane = t & 63;
    const float* kw2l = kw2 + (size_t)id * 65536;
    half8 vh, vl;
#pragma unroll
    for (int j = 0; j < 8; ++j) {
        const int k = ks * 16 + (lane >> 5) * 8 + j;
        const float v = kw2l[(size_t)k * 1024 + (lane & 31) * 32 + nt];
        const hf16 h = (hf16)v;
        vh[j] = h;
        vl[j] = (hf16)((v - (float)h) * 1024.0f);
    }
    half8* dst = (half8*)(Wpack + ((size_t)(id * 32 + nt) * 8 + ks * 2) * 512);
    dst[0 * 64 + lane] = vh;
    dst[1 * 64 + lane] = vl;
}

// ---------------- kb2 pre-permute: kb2C[id][nt][hi][r] = kb2[id][i(r,hi)*32+nt] -------
__global__ __launch_bounds__(256) void kprep_kernel(const float* __restrict__ kb2,
                                                    float* __restrict__ kb2C)
{
    const int id = blockIdx.x;
    const int t = threadIdx.x;
#pragma unroll
    for (int c = 0; c < 4; ++c) {
        const int ent = t * 4 + c;           // nt*32 + hi*16 + r
        const int nt = ent >> 5;
        const int hi = (ent >> 4) & 1;
        const int r = ent & 15;
        const int i = (r & 3) + 8 * (r >> 2) + 4 * hi;
        kb2C[(size_t)id * 1024 + ent] = kb2[(size_t)id * 1024 + i * 32 + nt];
    }
}

// ---------------- H pre-pack: all 14 uses, B-fragment lane order ----------------
// B-frag: lane l -> col (edge) = l&31, k = ks*16 + 8*(l>>5) + j.
// Hpack: [use(14)][tile(1024)][ks(4)][p(2)][lane(64)][j(8)] halves.
__global__ __launch_bounds__(256) void hprep_kernel(
    EA14 ea, const float* __restrict__ kw1, const float* __restrict__ kb1,
    hf16* __restrict__ Hpack)
{
    const int b = blockIdx.x;
    const int u = b >> 8;                 // use id 0..13
    const int tgrp = b & 255;
    const int t = threadIdx.x, l = t & 63, wv = t >> 6;
    const int tile = tgrp * 4 + wv;
    const int eg = tile * 32 + (l & 31);
    const float* kw1u = kw1 + (size_t)u * 320;
    const float* kb1u = kb1 + (size_t)u * 64;
    float ea5[5];
#pragma unroll
    for (int j = 0; j < 5; ++j) ea5[j] = ea.p[u][(size_t)eg * 5 + j];
    half8* hp = (half8*)Hpack;
#pragma unroll
    for (int ks = 0; ks < 4; ++ks) {
        half8 vh, vl;
#pragma unroll
        for (int j = 0; j < 8; ++j) {
            const int k = ks * 16 + (l >> 5) * 8 + j;
            float pre = kb1u[k];
#pragma unroll
            for (int q = 0; q < 5; ++q) pre = fmaf(ea5[q], kw1u[q * 64 + k], pre);
            const float H = gelu_f(pre);
            const hf16 hv = (hf16)H;
            vh[j] = hv;
            vl[j] = (hf16)((H - (float)hv) * 1024.0f);
        }
        const size_t fb = ((size_t)(u * 1024 + tile) * 8 + ks * 2) * 64;
        hp[fb + l] = vh;
        hp[fb + 64 + l] = vl;
    }
}

// ---------------- gemm: MFMA (W x H) + kb2 fold + in-reg dot + edge-order store -------
// grid = 1024 (XCD-swizzled: qid siblings share an XCD); block = 4 waves, wave -> 32-edge
// tile; qid selects 8 n-tiles. W staged via LDS double-buffer (shared by all 4 waves).
__global__ __launch_bounds__(256) void gemm_kernel(
    const float* __restrict__ xa, const float* __restrict__ xb,
    const int* __restrict__ esrc,
    const hf16* __restrict__ HpackU,
    const hf16* __restrict__ WpackL,
    const float* __restrict__ kb2CL,
    float* __restrict__ msgS)
{
    __shared__ __align__(16) hf16 wLDS[2 * 4096];   // 16 KiB: 2 x one n-tile of W frags
    half8* wl8 = (half8*)wLDS;

    // same-eblk qid siblings land on the same XCD
    const int lb = ((blockIdx.x & 7) << 7) + (blockIdx.x >> 3);
    const int eblk = lb >> 2;
    const int qid = lb & 3;
    const int t = threadIdx.x, l = t & 63, wv = t >> 6;
    const int tile = eblk * 4 + wv;

    // ---- H fragments (global, pre-packed, per-wave) ----
    const half8* hp = (const half8*)HpackU + (size_t)tile * 512;
    half8 Hh[4], Hl[4];
#pragma unroll
    for (int ks = 0; ks < 4; ++ks) {
        Hh[ks] = hp[(ks * 2 + 0) * 64 + l];
        Hl[ks] = hp[(ks * 2 + 1) * 64 + l];
    }

    // ---- gather xs in C-layout order: lane l -> edge (l&31), i = (r&3)+8*(r>>2)+4*hi ----
    const int hi = l >> 5;
    const int el = tile * 32 + (l & 31);
    const int src = esrc[el];
    float xsr[16];
#pragma unroll
    for (int c = 0; c < 4; ++c) {
        float4 v = *reinterpret_cast<const float4*>(xa + (size_t)src * 32 + c * 8 + hi * 4);
        if (xb) {
            float4 u = *reinterpret_cast<const float4*>(xb + (size_t)src * 32 + c * 8 + hi * 4);
            v.x += u.x; v.y += u.y; v.z += u.z; v.w += u.w;
        }
        xsr[c * 4 + 0] = v.x; xsr[c * 4 + 1] = v.y;
        xsr[c * 4 + 2] = v.z; xsr[c * 4 + 3] = v.w;
    }

    const half8* wsrc = (const half8*)(WpackL + (size_t)qid * 8 * 4096);
    const float* kbB = kb2CL + hi * 16;

    // ---- prologue: stage n-tile 0 into LDS buf 0 ----
    {
        half8 s0 = wsrc[t * 2 + 0];
        half8 s1 = wsrc[t * 2 + 1];
        wl8[t * 2 + 0] = s0;
        wl8[t * 2 + 1] = s1;
    }
    __syncthreads();

    float4 p4;
    int buf = 0;
#pragma unroll
    for (int nt8 = 0; nt8 < 8; ++nt8) {
        // issue next tile's W loads early (land during compute)
        half8 s0, s1;
        if (nt8 < 7) {
            s0 = wsrc[(nt8 + 1) * 512 + t * 2 + 0];
            s1 = wsrc[(nt8 + 1) * 512 + t * 2 + 1];
        }

        // W fragments from LDS
        half8 WH[4], WL[4];
#pragma unroll
        for (int ks = 0; ks < 4; ++ks) {
            WH[ks] = wl8[buf * 512 + (ks * 2 + 0) * 64 + l];
            WL[ks] = wl8[buf * 512 + (ks * 2 + 1) * 64 + l];
        }

        const int nt = qid * 8 + nt8;
        // kb2C for this tile (16 floats, uniform per half-wave)
        float kb[16];
#pragma unroll
        for (int c = 0; c < 4; ++c) {
            const float4 kv = *reinterpret_cast<const float4*>(kbB + nt * 32 + c * 4);
            kb[c * 4 + 0] = kv.x; kb[c * 4 + 1] = kv.y;
            kb[c * 4 + 2] = kv.z; kb[c * 4 + 3] = kv.w;
        }

        f32x16 ah = zero16(), ax = zero16();
#pragma unroll
        for (int ks = 0; ks < 4; ++ks) {
            ah = __builtin_amdgcn_mfma_f32_32x32x16_f16(WH[ks], Hh[ks], ah, 0, 0, 0);
            ax = __builtin_amdgcn_mfma_f32_32x32x16_f16(WL[ks], Hh[ks], ax, 0, 0, 0);
            ax = __builtin_amdgcn_mfma_f32_32x32x16_f16(WH[ks], Hl[ks], ax, 0, 0, 0);
        }
        float ph = 0.0f, px = 0.0f, pk = 0.0f;
#pragma unroll
        for (int r = 0; r < 16; ++r) {
            ph = fmaf(ah[r], xsr[r], ph);
            px = fmaf(ax[r], xsr[r], px);
            pk = fmaf(kb[r], xsr[r], pk);
        }
        float p = fmaf(px, 9.765625e-4f, ph) + pk;
        p += __shfl_xor(p, 32);
        p4[nt8 & 3] = p;
        if ((nt8 & 3) == 3 && l < 32)
            *reinterpret_cast<float4*>(msgS + (size_t)el * 32 + qid * 8 + (nt8 - 3)) = p4;

        // write next tile into the other buffer, then sync
        if (nt8 < 7) {
            wl8[(buf ^ 1) * 512 + t * 2 + 0] = s0;
            wl8[(buf ^ 1) * 512 + t * 2 + 1] = s1;
        }
        __syncthreads();
        buf ^= 1;
    }
}

// ---------------- node update: wave per node ----------------
// lanes: o = l&31, half = l>>5. msg rows read coalesced via eord; matvec split by half.
__global__ __launch_bounds__(256) void node_update_kernel(
    const float* __restrict__ xa, const float* __restrict__ xb,
    float* __restrict__ xout, const float* __restrict__ msgS,
    const int* __restrict__ off, const int* __restrict__ eord,
    const float* __restrict__ lw, const float* __restrict__ lb)
{
    __shared__ float lwS[1024];
#pragma unroll
    for (int c = 0; c < 4; ++c) lwS[threadIdx.x + 256 * c] = lw[threadIdx.x + 256 * c];
    __syncthreads();

    const int t = threadIdx.x, l = t & 63, wv = t >> 6;
    const int n = blockIdx.x * 4 + wv;
    const int o = l & 31, jj = l >> 5;

    const int b = off[n], e = off[n + 1];
    float sum = 0.0f;
    for (int j = b + jj; j < e; j += 2) {
        const int eid = eord[j];
        sum += msgS[(size_t)eid * 32 + o];
    }
    sum += __shfl_xor(sum, 32);
    const float inv = (e > b) ? 1.0f / (float)(e - b) : 0.0f;

    // matvec: half jj covers i in [jj*16, jj*16+16)
    float part = 0.0f;
#pragma unroll
    for (int c = 0; c < 4; ++c) {
        float4 v = *reinterpret_cast<const float4*>(xa + (size_t)n * 32 + jj * 16 + c * 4);
        if (xb) {
            float4 u = *reinterpret_cast<const float4*>(xb + (size_t)n * 32 + jj * 16 + c * 4);
            v.x += u.x; v.y += u.y; v.z += u.z; v.w += u.w;
        }
        part = fmaf(v.x, lwS[(jj * 16 + c * 4 + 0) * 32 + o], part);
        part = fmaf(v.y, lwS[(jj * 16 + c * 4 + 1) * 32 + o], part);
        part = fmaf(v.z, lwS[(jj * 16 + c * 4 + 2) * 32 + o], part);
        part = fmaf(v.w, lwS[(jj * 16 + c * 4 + 3) * 32 + o], part);
    }
    part += __shfl_xor(part, 32);

    const float acc = fmaf(sum, inv, lb[o]) + part;
    if (l < 32) xout[(size_t)n * 32 + o] = gelu_f(acc);
}

// ---------------- decoder ----------------
__global__ __launch_bounds__(256) void decode_kernel(
    const float* __restrict__ a, const float* __restrict__ b,
    const float* __restrict__ w1, const float* __restrict__ b1,
    const float* __restrict__ w2, const float* __restrict__ b2,
    float* __restrict__ out)
{
    const int n = blockIdx.x * 256 + threadIdx.x;
    float s[32];
#pragma unroll
    for (int i = 0; i < 32; ++i) s[i] = a[(size_t)n * 32 + i] + b[(size_t)n * 32 + i];
    float acc = b2[0];
#pragma unroll
    for (int j = 0; j < 16; ++j) {
        float h = b1[j];
#pragma unroll
        for (int i = 0; i < 32; ++i) h = fmaf(s[i], w1[i * 16 + j], h);
        acc = fmaf(gelu_f(h), w2[j], acc);
    }
    out[n] = acc;
}

extern "C" void kernel_launch(void* const* d_in, const int* in_sizes, int n_in,
                              void* d_out, int out_size, void* d_ws, size_t ws_size,
                              hipStream_t stream)
{
    const float* nodes = (const float*)d_in[0];
    const float* grid2 = (const float*)d_in[1];
    const int* ei[7];
    const float* ea[7];
    for (int s = 0; s < 7; ++s) {
        ei[s] = (const int*)d_in[2 + s];
        ea[s] = (const float*)d_in[9 + s];
    }
    const float* pw1 = (const float*)d_in[18];
    const float* pb1 = (const float*)d_in[19];
    const float* pw2 = (const float*)d_in[20];
    const float* pb2 = (const float*)d_in[21];
    const float* dw1 = (const float*)d_in[22];
    const float* db1 = (const float*)d_in[23];
    const float* dw2 = (const float*)d_in[24];
    const float* db2 = (const float*)d_in[25];
    const float* kw1 = (const float*)d_in[26];
    const float* kb1 = (const float*)d_in[27];
    const float* kw2 = (const float*)d_in[28];
    const float* kb2 = (const float*)d_in[29];
    const float* lw  = (const float*)d_in[30];
    const float* lb  = (const float*)d_in[31];

    // block i (param index) -> edge set
    const int i2s[7] = {0, 2, 4, 1, 3, 5, 6};

    float* ws  = (float*)d_ws;
    float* x0   = ws + 0 * (size_t)NL;
    float* n11  = ws + 1 * (size_t)NL;
    float* n12  = ws + 2 * (size_t)NL;
    float* n22  = ws + 3 * (size_t)NL;
    float* n23  = ws + 4 * (size_t)NL;
    float* n33  = ws + 5 * (size_t)NL;
    float* n32  = ws + 6 * (size_t)NL;
    float* n21  = ws + 7 * (size_t)NL;
    float* msgS = ws + 8 * (size_t)NL;                       // Ee*32 floats (4 MB)
    size_t cur = 8 * (size_t)NL + (size_t)Ee * 32;
    hf16* Wpack = (hf16*)(ws + cur);                         // 14*32*8*512 halves (3.5 MB)
    cur += (size_t)14 * 32 * 8 * 512 / 2;
    hf16* Hpack = (hf16*)(ws + cur);                         // 14*1024*8*512 halves (117 MB)
    cur += (size_t)14 * 1024 * 8 * 512 / 2;
    float* kb2C = ws + cur; cur += (size_t)14 * 1024;        // 57 KB
    int* deg_i  = (int*)(ws + cur); cur += (size_t)7 * Nn;
    int* cursor = (int*)(ws + cur); cur += (size_t)7 * Nn;
    int* off    = (int*)(ws + cur); cur += (size_t)7 * (Nn + 1) + 1;
    int* eord   = (int*)(ws + cur);

    proj_kernel<<<Nn / 256, 256, 0, stream>>>(nodes, grid2, pw1, pb1, pw2, pb2,
                                              x0, deg_i, cursor);

    EPtrs ep;
    for (int s = 0; s < 7; ++s) ep.p[s] = ei[s];
    count_deg_kernel<<<7 * Ee / 256, 256, 0, stream>>>(ep, deg_i);
    scan_kernel<<<7, 256, 0, stream>>>(deg_i, off);
    rank_kernel<<<7 * Ee / 256, 256, 0, stream>>>(ep, off, cursor, eord);
    wprep_kernel<<<14 * 32, 256, 0, stream>>>(kw2, Wpack);
    kprep_kernel<<<14, 256, 0, stream>>>(kb2, kb2C);

    EA14 ea14;
    for (int u = 0; u < 14; ++u) ea14.p[u] = ea[i2s[u >> 1]];
    hprep_kernel<<<14 * 256, 256, 0, stream>>>(ea14, kw1, kb1, Hpack);

    auto layer = [&](int i, int d, int s, const float* xa, const float* xb, float* xo) {
        const int id = i * 2 + d;
        gemm_kernel<<<1024, 256, 0, stream>>>(
            xa, xb, ei[s],
            Hpack + (size_t)id * 1024 * 4096,
            Wpack + (size_t)id * 32 * 4096,
            kb2C + (size_t)id * 1024, msgS);
        node_update_kernel<<<Nn / 4, 256, 0, stream>>>(
            xa, xb, xo, msgS, off + (size_t)s * (Nn + 1),
            eord + (size_t)s * Ee,
            lw + (size_t)id * 1024, lb + (size_t)id * 32);
    };
    auto gno_block = [&](int i, int s, const float* xa, const float* xb, float* xo) {
        layer(i, 0, s, xa, xb, xo);
        layer(i, 1, s, xo, nullptr, xo);
    };

    // block param index order: n11->0, n12->3, n22->1, n23->4, n33->2, n32->5, n21->6
    gno_block(0, 0, x0,  nullptr, n11);
    gno_block(3, 1, x0,  nullptr, n12);
    gno_block(1, 2, n12, nullptr, n22);
    gno_block(4, 3, n12, nullptr, n23);
    gno_block(2, 4, n23, nullptr, n33);
    gno_block(5, 5, n33, nullptr, n32);
    gno_block(6, 6, n32, n22,     n21);

    decode_kernel<<<Nn / 256, 256, 0, stream>>>(n11, n21, dw1, db1, dw2, db2, (float*)d_out);
}